// Round 1
// baseline (474.392 us; speedup 1.0000x reference)
//
#include <hip/hip_runtime.h>
#include <math.h>

namespace {
constexpr int Hdim = 128;
constexpr int Pn = 50000;
constexpr int Cn = 20000;
constexpr int Bn = 4;
constexpr int NClause = Bn * Cn;   // 80000
constexpr int NRows = Bn * Pn;     // 200000
}

// out = A * Bm (128x128), optionally写transposed: out[t][o] = sum_h A[o][h]*Bm[h][t]
template <bool TRANS>
__global__ void mm128_kernel(const float* __restrict__ A, const float* __restrict__ Bm,
                             float* __restrict__ out) {
    int o = blockIdx.x, t = threadIdx.x;
    float acc = 0.f;
#pragma unroll 8
    for (int h = 0; h < Hdim; ++h) acc = fmaf(A[o * Hdim + h], Bm[h * Hdim + t], acc);
    if (TRANS) out[t * Hdim + o] = acc;
    else out[o * Hdim + t] = acc;
}

__global__ void transpose128_kernel(const float* __restrict__ A, float* __restrict__ out) {
    int o = blockIdx.x, t = threadIdx.x;
    out[t * Hdim + o] = A[o * Hdim + t];
}

// bias_comb = W_cv*(W_ce*b_vc + b_ce) + b_cv
__global__ void fold_bias_kernel(const float* __restrict__ W_ce, const float* __restrict__ b_vc,
                                 const float* __restrict__ b_ce, const float* __restrict__ W_cv,
                                 const float* __restrict__ b_cv, float* __restrict__ bias_comb) {
    __shared__ float b1[Hdim];
    int o = threadIdx.x;
    float acc = b_ce[o];
    for (int h = 0; h < Hdim; ++h) acc = fmaf(W_ce[o * Hdim + h], b_vc[h], acc);
    b1[o] = acc;
    __syncthreads();
    float acc2 = b_cv[o];
    for (int h = 0; h < Hdim; ++h) acc2 = fmaf(W_cv[o * Hdim + h], b1[h], acc2);
    bias_comb[o] = acc2;
}

__global__ void hist_kernel(const int* __restrict__ ci, int* __restrict__ counts) {
    int fid = blockIdx.x * blockDim.x + threadIdx.x;
    if (fid >= NClause) return;
    int i0 = ci[fid * 3 + 0], i1 = ci[fid * 3 + 1], i2 = ci[fid * 3 + 2];
    atomicAdd(&counts[i0], 1);
    if (i1 != i0) atomicAdd(&counts[i1], 1);
    if (i2 != i0 && i2 != i1) atomicAdd(&counts[i2], 1);
}

__global__ __launch_bounds__(1024) void scan_kernel(const int* __restrict__ counts,
                                                    int* __restrict__ offsets) {
    __shared__ int lds[1024];
    int tid = threadIdx.x;
    constexpr int chunk = (Pn + 1023) / 1024;  // 49
    int base = tid * chunk;
    int end = (base + chunk < Pn) ? base + chunk : Pn;
    int s = 0;
    for (int i = base; i < end; ++i) s += counts[i];
    lds[tid] = s;
    __syncthreads();
    for (int off = 1; off < 1024; off <<= 1) {
        int v = lds[tid];
        int add = (tid >= off) ? lds[tid - off] : 0;
        __syncthreads();
        lds[tid] = v + add;
        __syncthreads();
    }
    int run = (tid > 0) ? lds[tid - 1] : 0;
    for (int i = base; i < end; ++i) { offsets[i] = run; run += counts[i]; }
    if (tid == 0) offsets[Pn] = lds[1023];
}

__global__ void fill_kernel(const int* __restrict__ ci, const int* __restrict__ offsets,
                            int* __restrict__ cursor, int* __restrict__ entries) {
    int fid = blockIdx.x * blockDim.x + threadIdx.x;
    if (fid >= NClause) return;
    int i0 = ci[fid * 3 + 0], i1 = ci[fid * 3 + 1], i2 = ci[fid * 3 + 2];
    int pos = atomicAdd(&cursor[i0], 1);
    entries[offsets[i0] + pos] = fid;
    if (i1 != i0) { pos = atomicAdd(&cursor[i1], 1); entries[offsets[i1] + pos] = fid; }
    if (i2 != i0 && i2 != i1) { pos = atomicAdd(&cursor[i2], 1); entries[offsets[i2] + pos] = fid; }
}

// M[fid][o] = sum_t meanG[fid][t]*WT[t][o] + bias[o]; meanG = mean_k (vs0[b,idx]+msgs[idx])
__global__ __launch_bounds__(256) void clause_kernel(
    const int* __restrict__ ci, const float* __restrict__ vs0, const float* __restrict__ msgs,
    const float* __restrict__ WT, const float* __restrict__ bias, float* __restrict__ M) {
    __shared__ float gm[32][Hdim];
    int tid = threadIdx.x;
    int block0 = blockIdx.x * 32;
#pragma unroll
    for (int pass = 0; pass < 16; ++pass) {
        int r = pass * 2 + (tid >> 7);
        int col = tid & 127;
        int fid = block0 + r;
        int b = fid / Cn;
        int i0 = ci[fid * 3 + 0], i1 = ci[fid * 3 + 1], i2 = ci[fid * 3 + 2];
        size_t vb = (size_t)b * Pn * Hdim;
        float s = vs0[vb + (size_t)i0 * Hdim + col] + msgs[(size_t)i0 * Hdim + col] +
                  vs0[vb + (size_t)i1 * Hdim + col] + msgs[(size_t)i1 * Hdim + col] +
                  vs0[vb + (size_t)i2 * Hdim + col] + msgs[(size_t)i2 * Hdim + col];
        gm[r][col] = s * (1.f / 3.f);
    }
    __syncthreads();
    int rg = tid >> 5, cg = tid & 31;
    float acc[4][4] = {};
#pragma unroll 4
    for (int t = 0; t < Hdim; t += 4) {
        float a[4][4], w[4][4];
#pragma unroll
        for (int i = 0; i < 4; ++i) {
            float4 v = *(const float4*)&gm[rg * 4 + i][t];
            a[i][0] = v.x; a[i][1] = v.y; a[i][2] = v.z; a[i][3] = v.w;
        }
#pragma unroll
        for (int u = 0; u < 4; ++u) {
            float4 v = *(const float4*)&WT[(size_t)(t + u) * Hdim + cg * 4];
            w[u][0] = v.x; w[u][1] = v.y; w[u][2] = v.z; w[u][3] = v.w;
        }
#pragma unroll
        for (int i = 0; i < 4; ++i)
#pragma unroll
            for (int u = 0; u < 4; ++u)
#pragma unroll
                for (int j = 0; j < 4; ++j)
                    acc[i][j] = fmaf(a[i][u], w[u][j], acc[i][j]);
    }
    float4 bv = *(const float4*)&bias[cg * 4];
    float bb[4] = {bv.x, bv.y, bv.z, bv.w};
#pragma unroll
    for (int i = 0; i < 4; ++i) {
        float4 o4;
        o4.x = acc[i][0] + bb[0];
        o4.y = acc[i][1] + bb[1];
        o4.z = acc[i][2] + bb[2];
        o4.w = acc[i][3] + bb[3];
        *(float4*)&M[(size_t)(block0 + rg * 4 + i) * Hdim + cg * 4] = o4;
    }
}

// msgs_acc[p] += (sum over CSR entries of M[cid]) / counts[p]
__global__ __launch_bounds__(256) void var_kernel(const float* __restrict__ M,
                                                  const int* __restrict__ counts,
                                                  const int* __restrict__ offsets,
                                                  const int* __restrict__ entries,
                                                  float* __restrict__ msgs) {
    int wave = threadIdx.x >> 6;
    int lane = threadIdx.x & 63;
    int p = blockIdx.x * 4 + wave;
    if (p >= Pn) return;
    int deg = counts[p];
    int off = offsets[p];
    float a0 = 0.f, a1 = 0.f;
    for (int e = 0; e < deg; ++e) {
        int cid = entries[off + e];
        const float* mr = &M[(size_t)cid * Hdim];
        a0 += mr[lane];
        a1 += mr[lane + 64];
    }
    if (deg > 0) {
        float inv = 1.f / (float)deg;
        a0 *= inv; a1 *= inv;
    }
    msgs[(size_t)p * Hdim + lane] += a0;
    msgs[(size_t)p * Hdim + lane + 64] += a1;
}

// out[row] = sigmoid( sum_o W_s2[o]*relu( sum_t v[row][t]*WT1[t][o] + b_s1[o] ) + b_s2 )
__global__ __launch_bounds__(256) void final_kernel(
    const float* __restrict__ vs0, const float* __restrict__ msgs, const float* __restrict__ WT1,
    const float* __restrict__ b_s1, const float* __restrict__ W_s2, const float* __restrict__ b_s2,
    float* __restrict__ out) {
    __shared__ float vrow[32][Hdim];
    int tid = threadIdx.x;
    int block0 = blockIdx.x * 32;
#pragma unroll
    for (int pass = 0; pass < 16; ++pass) {
        int r = pass * 2 + (tid >> 7);
        int col = tid & 127;
        int row = block0 + r;     // row = b*Pn + p
        int p = row % Pn;
        vrow[r][col] = vs0[(size_t)row * Hdim + col] + msgs[(size_t)p * Hdim + col];
    }
    __syncthreads();
    int rg = tid >> 5, cg = tid & 31;
    float acc[4][4] = {};
#pragma unroll 4
    for (int t = 0; t < Hdim; t += 4) {
        float a[4][4], w[4][4];
#pragma unroll
        for (int i = 0; i < 4; ++i) {
            float4 v = *(const float4*)&vrow[rg * 4 + i][t];
            a[i][0] = v.x; a[i][1] = v.y; a[i][2] = v.z; a[i][3] = v.w;
        }
#pragma unroll
        for (int u = 0; u < 4; ++u) {
            float4 v = *(const float4*)&WT1[(size_t)(t + u) * Hdim + cg * 4];
            w[u][0] = v.x; w[u][1] = v.y; w[u][2] = v.z; w[u][3] = v.w;
        }
#pragma unroll
        for (int i = 0; i < 4; ++i)
#pragma unroll
            for (int u = 0; u < 4; ++u)
#pragma unroll
                for (int j = 0; j < 4; ++j)
                    acc[i][j] = fmaf(a[i][u], w[u][j], acc[i][j]);
    }
    float4 ws2v = *(const float4*)&W_s2[cg * 4];
    float ws2[4] = {ws2v.x, ws2v.y, ws2v.z, ws2v.w};
    float4 bs1v = *(const float4*)&b_s1[cg * 4];
    float bs1[4] = {bs1v.x, bs1v.y, bs1v.z, bs1v.w};
    float part[4];
#pragma unroll
    for (int i = 0; i < 4; ++i) {
        float su = 0.f;
#pragma unroll
        for (int j = 0; j < 4; ++j) su = fmaf(fmaxf(acc[i][j] + bs1[j], 0.f), ws2[j], su);
        part[i] = su;
    }
#pragma unroll
    for (int m = 1; m < 32; m <<= 1)
#pragma unroll
        for (int i = 0; i < 4; ++i) part[i] += __shfl_xor(part[i], m, 64);
    if (cg == 0) {
        float lb = b_s2[0];
#pragma unroll
        for (int i = 0; i < 4; ++i) {
            float logit = part[i] + lb;
            out[block0 + rg * 4 + i] = 1.f / (1.f + expf(-logit));
        }
    }
}

extern "C" void kernel_launch(void* const* d_in, const int* in_sizes, int n_in,
                              void* d_out, int out_size, void* d_ws, size_t ws_size,
                              hipStream_t stream) {
    (void)in_sizes; (void)n_in; (void)out_size; (void)ws_size;
    const int* ci = (const int*)d_in[0];
    const float* vs0 = (const float*)d_in[1];
    const float* W_vc = (const float*)d_in[2];
    const float* b_vc = (const float*)d_in[3];
    const float* W_ce = (const float*)d_in[4];
    const float* b_ce = (const float*)d_in[5];
    const float* W_cv = (const float*)d_in[6];
    const float* b_cv = (const float*)d_in[7];
    const float* W_s1 = (const float*)d_in[8];
    const float* b_s1 = (const float*)d_in[9];
    const float* W_s2 = (const float*)d_in[10];
    const float* b_s2 = (const float*)d_in[11];
    float* out = (float*)d_out;

    char* ws = (char*)d_ws;
    size_t off = 0;
    auto alloc = [&](size_t bytes) -> void* {
        off = (off + 255) & ~(size_t)255;
        void* p = ws + off;
        off += bytes;
        return p;
    };
    float* temp1 = (float*)alloc(Hdim * Hdim * 4);            // W_ce*W_vc
    float* WT = (float*)alloc(Hdim * Hdim * 4);               // (W_cv*temp1)^T
    float* WT1 = (float*)alloc(Hdim * Hdim * 4);              // W_s1^T
    float* bias_comb = (float*)alloc(Hdim * 4);
    int* counts = (int*)alloc(Pn * 4);
    int* cursor = (int*)alloc(Pn * 4);
    int* offsets = (int*)alloc((Pn + 1) * 4);
    int* entries = (int*)alloc((size_t)NClause * 3 * 4);
    float* M = (float*)alloc((size_t)NClause * Hdim * 4);     // 40.96 MB
    float* msgs = (float*)alloc((size_t)Pn * Hdim * 4);       // 25.6 MB

    hipMemsetAsync(counts, 0, Pn * 4, stream);
    hipMemsetAsync(cursor, 0, Pn * 4, stream);
    hipMemsetAsync(msgs, 0, (size_t)Pn * Hdim * 4, stream);

    // fold weights: W_comb^T = (W_cv * (W_ce * W_vc))^T, bias_comb
    mm128_kernel<false><<<Hdim, Hdim, 0, stream>>>(W_ce, W_vc, temp1);
    mm128_kernel<true><<<Hdim, Hdim, 0, stream>>>(W_cv, temp1, WT);
    fold_bias_kernel<<<1, Hdim, 0, stream>>>(W_ce, b_vc, b_ce, W_cv, b_cv, bias_comb);
    transpose128_kernel<<<Hdim, Hdim, 0, stream>>>(W_s1, WT1);

    // CSR build
    int nb = (NClause + 255) / 256;
    hist_kernel<<<nb, 256, 0, stream>>>(ci, counts);
    scan_kernel<<<1, 1024, 0, stream>>>(counts, offsets);
    fill_kernel<<<nb, 256, 0, stream>>>(ci, offsets, cursor, entries);

    for (int it = 0; it < 2; ++it) {
        clause_kernel<<<NClause / 32, 256, 0, stream>>>(ci, vs0, msgs, WT, bias_comb, M);
        var_kernel<<<(Pn + 3) / 4, 256, 0, stream>>>(M, counts, offsets, entries, msgs);
    }
    final_kernel<<<NRows / 32, 256, 0, stream>>>(vs0, msgs, WT1, b_s1, W_s2, b_s2, out);
}

// Round 2
// 298.281 us; speedup vs baseline: 1.5904x; 1.5904x over previous
//
#include <hip/hip_runtime.h>
#include <math.h>

using u16 = unsigned short;
using u32 = unsigned int;

namespace {
constexpr int Hdim = 128;
constexpr int Pn = 50000;
constexpr int Cn = 20000;
constexpr int Bn = 4;
constexpr int NClause = Bn * Cn;   // 80000
constexpr int NRows = Bn * Pn;     // 200000
}

typedef __attribute__((ext_vector_type(4))) float f32x4;
typedef __attribute__((ext_vector_type(8))) short bf16x8;

static __device__ __forceinline__ float bf2f(u16 v) {
    u32 u = ((u32)v) << 16;
    return __builtin_bit_cast(float, u);
}
static __device__ __forceinline__ u16 f2bf(float f) {
    u32 u = __builtin_bit_cast(u32, f);
    u32 r = u + 0x7FFFu + ((u >> 16) & 1u);
    return (u16)(r >> 16);
}

// C = A * B (128x128 fp32, row-major)
__global__ void mm128_kernel(const float* __restrict__ A, const float* __restrict__ Bm,
                             float* __restrict__ out) {
    int o = blockIdx.x, t = threadIdx.x;
    float acc = 0.f;
#pragma unroll 8
    for (int h = 0; h < Hdim; ++h) acc = fmaf(A[o * Hdim + h], Bm[h * Hdim + t], acc);
    out[o * Hdim + t] = acc;
}

// bias_comb = W_cv*(W_ce*b_vc + b_ce) + b_cv
__global__ void fold_bias_kernel(const float* __restrict__ W_ce, const float* __restrict__ b_vc,
                                 const float* __restrict__ b_ce, const float* __restrict__ W_cv,
                                 const float* __restrict__ b_cv, float* __restrict__ bias_comb) {
    __shared__ float b1[Hdim];
    int o = threadIdx.x;
    float acc = b_ce[o];
    for (int h = 0; h < Hdim; ++h) acc = fmaf(W_ce[o * Hdim + h], b_vc[h], acc);
    b1[o] = acc;
    __syncthreads();
    float acc2 = b_cv[o];
    for (int h = 0; h < Hdim; ++h) acc2 = fmaf(W_cv[o * Hdim + h], b1[h], acc2);
    bias_comb[o] = acc2;
}

// src is row-major [n][k] fp32 (i.e. B^T). Pack into per-lane MFMA B-frag layout:
// dst[((nt*4+ks)*64 + lane)*8 + j] = bf16(src[nt*16 + (lane&15)][ks*32 + (lane>>4)*8 + j])
__global__ void pack_b_kernel(const float* __restrict__ src, u16* __restrict__ dst) {
    int g = blockIdx.x * blockDim.x + threadIdx.x;   // 2048 total
    int lane = g & 63;
    int n = ((g >> 8) * 16) + (lane & 15);
    int k0 = ((g >> 6) & 3) * 32 + (lane >> 4) * 8;
    bf16x8 o;
#pragma unroll
    for (int j = 0; j < 8; ++j) o[j] = (short)f2bf(src[n * Hdim + k0 + j]);
    *(bf16x8*)(dst + (size_t)g * 8) = o;
}

__global__ void convert_kernel(const float* __restrict__ src, u16* __restrict__ dst) {
    int g = blockIdx.x * blockDim.x + threadIdx.x;   // one per 8 floats
    f32x4 a = ((const f32x4*)src)[(size_t)g * 2];
    f32x4 b = ((const f32x4*)src)[(size_t)g * 2 + 1];
    bf16x8 o;
    o[0] = (short)f2bf(a.x); o[1] = (short)f2bf(a.y);
    o[2] = (short)f2bf(a.z); o[3] = (short)f2bf(a.w);
    o[4] = (short)f2bf(b.x); o[5] = (short)f2bf(b.y);
    o[6] = (short)f2bf(b.z); o[7] = (short)f2bf(b.w);
    *(bf16x8*)(dst + (size_t)g * 8) = o;
}

__global__ void hist_kernel(const int* __restrict__ ci, int* __restrict__ counts) {
    int fid = blockIdx.x * blockDim.x + threadIdx.x;
    if (fid >= NClause) return;
    int i0 = ci[fid * 3 + 0], i1 = ci[fid * 3 + 1], i2 = ci[fid * 3 + 2];
    atomicAdd(&counts[i0], 1);
    if (i1 != i0) atomicAdd(&counts[i1], 1);
    if (i2 != i0 && i2 != i1) atomicAdd(&counts[i2], 1);
}

__global__ __launch_bounds__(1024) void scan_kernel(const int* __restrict__ counts,
                                                    int* __restrict__ offsets) {
    __shared__ int lds[1024];
    int tid = threadIdx.x;
    constexpr int chunk = (Pn + 1023) / 1024;  // 49
    int base = tid * chunk;
    int end = (base + chunk < Pn) ? base + chunk : Pn;
    int s = 0;
    for (int i = base; i < end; ++i) s += counts[i];
    lds[tid] = s;
    __syncthreads();
    for (int off = 1; off < 1024; off <<= 1) {
        int v = lds[tid];
        int add = (tid >= off) ? lds[tid - off] : 0;
        __syncthreads();
        lds[tid] = v + add;
        __syncthreads();
    }
    int run = (tid > 0) ? lds[tid - 1] : 0;
    for (int i = base; i < end; ++i) { offsets[i] = run; run += counts[i]; }
    if (tid == 0) offsets[Pn] = lds[1023];
}

__global__ void fill_kernel(const int* __restrict__ ci, const int* __restrict__ offsets,
                            int* __restrict__ cursor, int* __restrict__ entries) {
    int fid = blockIdx.x * blockDim.x + threadIdx.x;
    if (fid >= NClause) return;
    int i0 = ci[fid * 3 + 0], i1 = ci[fid * 3 + 1], i2 = ci[fid * 3 + 2];
    int pos = atomicAdd(&cursor[i0], 1);
    entries[offsets[i0] + pos] = fid;
    if (i1 != i0) { pos = atomicAdd(&cursor[i1], 1); entries[offsets[i1] + pos] = fid; }
    if (i2 != i0 && i2 != i1) { pos = atomicAdd(&cursor[i2], 1); entries[offsets[i2] + pos] = fid; }
}

// M[fid][o] = bf16( sum_t meanG[fid][t]*Wcomb[o][t] + bias[o] )
// meanG = mean over 3 gathered rows of (vsb + msgs)
__global__ __launch_bounds__(256) void clause_kernel(
    const int* __restrict__ ci, const u16* __restrict__ vsb, const u16* __restrict__ msgs,
    const u16* __restrict__ Bpack, const float* __restrict__ bias, u16* __restrict__ M,
    int use_msgs) {
    __shared__ __align__(16) u16 Atile[64 * 136];   // 272B row pitch
    __shared__ __align__(16) u16 Btile[128 * 128];
    int tid = threadIdx.x;
    int block0 = blockIdx.x * 64;
    {   // stage packed B (32KB)
        const bf16x8* s = (const bf16x8*)Bpack;
        bf16x8* d = (bf16x8*)Btile;
#pragma unroll
        for (int i = 0; i < 8; ++i) d[tid + i * 256] = s[tid + i * 256];
    }
#pragma unroll
    for (int pass = 0; pass < 4; ++pass) {
        int t = pass * 256 + tid;
        int r = t >> 4, seg = t & 15;
        int fid = block0 + r;
        int b = fid / Cn;
        int i0 = ci[fid * 3 + 0], i1 = ci[fid * 3 + 1], i2 = ci[fid * 3 + 2];
        size_t vb = (size_t)b * Pn * Hdim;
        int co = seg * 8;
        bf16x8 v0 = *(const bf16x8*)(vsb + vb + (size_t)i0 * Hdim + co);
        bf16x8 v1 = *(const bf16x8*)(vsb + vb + (size_t)i1 * Hdim + co);
        bf16x8 v2 = *(const bf16x8*)(vsb + vb + (size_t)i2 * Hdim + co);
        float s[8];
#pragma unroll
        for (int j = 0; j < 8; ++j)
            s[j] = bf2f((u16)v0[j]) + bf2f((u16)v1[j]) + bf2f((u16)v2[j]);
        if (use_msgs) {
            bf16x8 m0 = *(const bf16x8*)(msgs + (size_t)i0 * Hdim + co);
            bf16x8 m1 = *(const bf16x8*)(msgs + (size_t)i1 * Hdim + co);
            bf16x8 m2 = *(const bf16x8*)(msgs + (size_t)i2 * Hdim + co);
#pragma unroll
            for (int j = 0; j < 8; ++j)
                s[j] += bf2f((u16)m0[j]) + bf2f((u16)m1[j]) + bf2f((u16)m2[j]);
        }
        bf16x8 o;
#pragma unroll
        for (int j = 0; j < 8; ++j) o[j] = (short)f2bf(s[j] * (1.f / 3.f));
        *(bf16x8*)(&Atile[r * 136 + seg * 8]) = o;
    }
    __syncthreads();
    int w = tid >> 6, l = tid & 63;
    int arow = w * 16 + (l & 15);
    int kofs = (l >> 4) * 8;
    f32x4 acc[8];
#pragma unroll
    for (int nt = 0; nt < 8; ++nt) acc[nt] = (f32x4){0.f, 0.f, 0.f, 0.f};
#pragma unroll
    for (int ks = 0; ks < 4; ++ks) {
        bf16x8 af = *(const bf16x8*)(&Atile[arow * 136 + ks * 32 + kofs]);
#pragma unroll
        for (int nt = 0; nt < 8; ++nt) {
            bf16x8 bfr = *(const bf16x8*)(&Btile[((nt * 4 + ks) * 64 + l) * 8]);
            acc[nt] = __builtin_amdgcn_mfma_f32_16x16x32_bf16(af, bfr, acc[nt], 0, 0, 0);
        }
    }
    __syncthreads();   // done reading Atile; reuse as output staging
    int crow = w * 16 + (l >> 4) * 4;
#pragma unroll
    for (int nt = 0; nt < 8; ++nt) {
        int col = nt * 16 + (l & 15);
        float bc = bias[col];
#pragma unroll
        for (int reg = 0; reg < 4; ++reg)
            Atile[(crow + reg) * 136 + col] = f2bf(acc[nt][reg] + bc);
    }
    __syncthreads();
#pragma unroll
    for (int pass = 0; pass < 4; ++pass) {
        int t = pass * 256 + tid;
        int r = t >> 4, seg = t & 15;
        *(bf16x8*)(M + (size_t)(block0 + r) * Hdim + seg * 8) =
            *(const bf16x8*)(&Atile[r * 136 + seg * 8]);
    }
}

// msgs[p] += mean over CSR entries of M[fid]
__global__ __launch_bounds__(256) void var_kernel(const u16* __restrict__ M,
                                                  const int* __restrict__ counts,
                                                  const int* __restrict__ offsets,
                                                  const int* __restrict__ entries,
                                                  u16* __restrict__ msgs) {
    int wave = threadIdx.x >> 6, lane = threadIdx.x & 63;
    int p = blockIdx.x * 4 + wave;
    if (p >= Pn) return;
    int deg = counts[p], off = offsets[p];
    float a0 = 0.f, a1 = 0.f;
    for (int e = 0; e < deg; ++e) {
        int cid = entries[off + e];
        u32 v = *(const u32*)(M + (size_t)cid * Hdim + lane * 2);
        a0 += bf2f((u16)(v & 0xffffu));
        a1 += bf2f((u16)(v >> 16));
    }
    if (deg > 0) { float inv = 1.f / (float)deg; a0 *= inv; a1 *= inv; }
    u32* mp = (u32*)(msgs + (size_t)p * Hdim + lane * 2);
    u32 old = *mp;
    float o0 = bf2f((u16)(old & 0xffffu)) + a0;
    float o1 = bf2f((u16)(old >> 16)) + a1;
    *mp = (u32)f2bf(o0) | ((u32)f2bf(o1) << 16);
}

// out[row] = sigmoid( W_s2 . relu( (vsb[row]+msgs[row%Pn]) * W_s1^T + b_s1 ) + b_s2 )
__global__ __launch_bounds__(256) void final_kernel(
    const u16* __restrict__ vsb, const u16* __restrict__ msgs, const u16* __restrict__ Bpack,
    const float* __restrict__ b_s1, const float* __restrict__ W_s2, const float* __restrict__ b_s2,
    float* __restrict__ out) {
    __shared__ __align__(16) u16 Atile[64 * 136];
    __shared__ __align__(16) u16 Btile[128 * 128];
    int tid = threadIdx.x;
    int block0 = blockIdx.x * 64;
    {
        const bf16x8* s = (const bf16x8*)Bpack;
        bf16x8* d = (bf16x8*)Btile;
#pragma unroll
        for (int i = 0; i < 8; ++i) d[tid + i * 256] = s[tid + i * 256];
    }
#pragma unroll
    for (int pass = 0; pass < 4; ++pass) {
        int t = pass * 256 + tid;
        int r = t >> 4, seg = t & 15;
        int row = block0 + r;
        int p = row % Pn;
        int co = seg * 8;
        bf16x8 v = *(const bf16x8*)(vsb + (size_t)row * Hdim + co);
        bf16x8 m = *(const bf16x8*)(msgs + (size_t)p * Hdim + co);
        bf16x8 o;
#pragma unroll
        for (int j = 0; j < 8; ++j) o[j] = (short)f2bf(bf2f((u16)v[j]) + bf2f((u16)m[j]));
        *(bf16x8*)(&Atile[r * 136 + seg * 8]) = o;
    }
    __syncthreads();
    int w = tid >> 6, l = tid & 63;
    int arow = w * 16 + (l & 15);
    int kofs = (l >> 4) * 8;
    f32x4 acc[8];
#pragma unroll
    for (int nt = 0; nt < 8; ++nt) acc[nt] = (f32x4){0.f, 0.f, 0.f, 0.f};
#pragma unroll
    for (int ks = 0; ks < 4; ++ks) {
        bf16x8 af = *(const bf16x8*)(&Atile[arow * 136 + ks * 32 + kofs]);
#pragma unroll
        for (int nt = 0; nt < 8; ++nt) {
            bf16x8 bfr = *(const bf16x8*)(&Btile[((nt * 4 + ks) * 64 + l) * 8]);
            acc[nt] = __builtin_amdgcn_mfma_f32_16x16x32_bf16(af, bfr, acc[nt], 0, 0, 0);
        }
    }
    float part[4] = {0.f, 0.f, 0.f, 0.f};
#pragma unroll
    for (int nt = 0; nt < 8; ++nt) {
        int col = nt * 16 + (l & 15);
        float b1 = b_s1[col], w2 = W_s2[col];
#pragma unroll
        for (int reg = 0; reg < 4; ++reg)
            part[reg] += fmaxf(acc[nt][reg] + b1, 0.f) * w2;
    }
#pragma unroll
    for (int m = 1; m < 16; m <<= 1)
#pragma unroll
        for (int reg = 0; reg < 4; ++reg) part[reg] += __shfl_xor(part[reg], m, 64);
    if ((l & 15) == 0) {
        float lb = b_s2[0];
        int row0 = block0 + w * 16 + (l >> 4) * 4;
#pragma unroll
        for (int reg = 0; reg < 4; ++reg)
            out[row0 + reg] = 1.f / (1.f + expf(-(part[reg] + lb)));
    }
}

extern "C" void kernel_launch(void* const* d_in, const int* in_sizes, int n_in,
                              void* d_out, int out_size, void* d_ws, size_t ws_size,
                              hipStream_t stream) {
    (void)in_sizes; (void)n_in; (void)out_size; (void)ws_size;
    const int* ci = (const int*)d_in[0];
    const float* vs0 = (const float*)d_in[1];
    const float* W_vc = (const float*)d_in[2];
    const float* b_vc = (const float*)d_in[3];
    const float* W_ce = (const float*)d_in[4];
    const float* b_ce = (const float*)d_in[5];
    const float* W_cv = (const float*)d_in[6];
    const float* b_cv = (const float*)d_in[7];
    const float* W_s1 = (const float*)d_in[8];
    const float* b_s1 = (const float*)d_in[9];
    const float* W_s2 = (const float*)d_in[10];
    const float* b_s2 = (const float*)d_in[11];
    float* out = (float*)d_out;

    char* ws = (char*)d_ws;
    size_t off = 0;
    auto alloc = [&](size_t bytes) -> void* {
        off = (off + 255) & ~(size_t)255;
        void* p = ws + off;
        off += bytes;
        return p;
    };
    float* temp1 = (float*)alloc(Hdim * Hdim * 4);
    float* Wcomb = (float*)alloc(Hdim * Hdim * 4);
    float* bias_comb = (float*)alloc(Hdim * 4);
    u16* WcombPack = (u16*)alloc(Hdim * Hdim * 2);
    u16* Ws1Pack = (u16*)alloc(Hdim * Hdim * 2);
    int* counts = (int*)alloc(Pn * 4);
    int* cursor = (int*)alloc(Pn * 4);
    int* offsets = (int*)alloc((Pn + 1) * 4);
    int* entries = (int*)alloc((size_t)NClause * 3 * 4);
    u16* M = (u16*)alloc((size_t)NClause * Hdim * 2);      // 20.5 MB
    u16* msgs = (u16*)alloc((size_t)Pn * Hdim * 2);        // 12.8 MB
    u16* vsb = (u16*)alloc((size_t)NRows * Hdim * 2);      // 51.2 MB

    hipMemsetAsync(counts, 0, Pn * 4, stream);
    hipMemsetAsync(cursor, 0, Pn * 4, stream);
    hipMemsetAsync(msgs, 0, (size_t)Pn * Hdim * 2, stream);

    // weight fold + pack
    mm128_kernel<<<Hdim, Hdim, 0, stream>>>(W_ce, W_vc, temp1);
    mm128_kernel<<<Hdim, Hdim, 0, stream>>>(W_cv, temp1, Wcomb);
    fold_bias_kernel<<<1, Hdim, 0, stream>>>(W_ce, b_vc, b_ce, W_cv, b_cv, bias_comb);
    pack_b_kernel<<<8, 256, 0, stream>>>(Wcomb, WcombPack);
    pack_b_kernel<<<8, 256, 0, stream>>>(W_s1, Ws1Pack);

    // bf16 copy of variable_states
    convert_kernel<<<(NRows * Hdim / 8) / 256, 256, 0, stream>>>(vs0, vsb);

    // CSR build
    int nb = (NClause + 255) / 256;
    hist_kernel<<<nb, 256, 0, stream>>>(ci, counts);
    scan_kernel<<<1, 1024, 0, stream>>>(counts, offsets);
    fill_kernel<<<nb, 256, 0, stream>>>(ci, offsets, cursor, entries);

    for (int it = 0; it < 2; ++it) {
        clause_kernel<<<NClause / 64, 256, 0, stream>>>(ci, vsb, msgs, WcombPack, bias_comb, M, it);
        var_kernel<<<(Pn + 3) / 4, 256, 0, stream>>>(M, counts, offsets, entries, msgs);
    }
    final_kernel<<<NRows / 64, 256, 0, stream>>>(vsb, msgs, Ws1Pack, b_s1, W_s2, b_s2, out);
}

// Round 3
// 206.324 us; speedup vs baseline: 2.2993x; 1.4457x over previous
//
#include <hip/hip_runtime.h>
#include <math.h>

using u16 = unsigned short;
using u32 = unsigned int;

namespace {
constexpr int Hdim = 128;
constexpr int Pn = 50000;
constexpr int Cn = 20000;
constexpr int Bn = 4;
constexpr int NClause = Bn * Cn;   // 80000
constexpr int NRows = Bn * Pn;     // 200000
constexpr int CAP = 64;            // max clauses per variable (Poisson λ=4.8; P(≥64)≈e⁻¹⁵⁰)
}

typedef __attribute__((ext_vector_type(4))) float f32x4;
typedef __attribute__((ext_vector_type(8))) short bf16x8;

static __device__ __forceinline__ float bf2f(u16 v) {
    u32 u = ((u32)v) << 16;
    return __builtin_bit_cast(float, u);
}
static __device__ __forceinline__ u16 f2bf(float f) {
    u32 u = __builtin_bit_cast(u32, f);
    u32 r = u + 0x7FFFu + ((u >> 16) & 1u);
    return (u16)(r >> 16);
}

// C = A * B (128x128 fp32, row-major)
__global__ void mm128_kernel(const float* __restrict__ A, const float* __restrict__ Bm,
                             float* __restrict__ out) {
    int o = blockIdx.x, t = threadIdx.x;
    float acc = 0.f;
#pragma unroll 8
    for (int h = 0; h < Hdim; ++h) acc = fmaf(A[o * Hdim + h], Bm[h * Hdim + t], acc);
    out[o * Hdim + t] = acc;
}

// bias_comb = W_cv*(W_ce*b_vc + b_ce) + b_cv
__global__ void fold_bias_kernel(const float* __restrict__ W_ce, const float* __restrict__ b_vc,
                                 const float* __restrict__ b_ce, const float* __restrict__ W_cv,
                                 const float* __restrict__ b_cv, float* __restrict__ bias_comb) {
    __shared__ float b1[Hdim];
    int o = threadIdx.x;
    float acc = b_ce[o];
    for (int h = 0; h < Hdim; ++h) acc = fmaf(W_ce[o * Hdim + h], b_vc[h], acc);
    b1[o] = acc;
    __syncthreads();
    float acc2 = b_cv[o];
    for (int h = 0; h < Hdim; ++h) acc2 = fmaf(W_cv[o * Hdim + h], b1[h], acc2);
    bias_comb[o] = acc2;
}

// src is row-major [n][k] fp32 (i.e. B^T). Pack into per-lane MFMA B-frag layout:
// dst[((nt*4+ks)*64 + lane)*8 + j] = bf16(src[nt*16 + (lane&15)][ks*32 + (lane>>4)*8 + j])
__global__ void pack_b_kernel(const float* __restrict__ src, u16* __restrict__ dst) {
    int g = blockIdx.x * blockDim.x + threadIdx.x;   // 2048 total
    int lane = g & 63;
    int n = ((g >> 8) * 16) + (lane & 15);
    int k0 = ((g >> 6) & 3) * 32 + (lane >> 4) * 8;
    bf16x8 o;
#pragma unroll
    for (int j = 0; j < 8; ++j) o[j] = (short)f2bf(src[n * Hdim + k0 + j]);
    *(bf16x8*)(dst + (size_t)g * 8) = o;
}

__global__ void convert_kernel(const float* __restrict__ src, u16* __restrict__ dst) {
    int g = blockIdx.x * blockDim.x + threadIdx.x;   // one per 8 floats
    f32x4 a = ((const f32x4*)src)[(size_t)g * 2];
    f32x4 b = ((const f32x4*)src)[(size_t)g * 2 + 1];
    bf16x8 o;
    o[0] = (short)f2bf(a.x); o[1] = (short)f2bf(a.y);
    o[2] = (short)f2bf(a.z); o[3] = (short)f2bf(a.w);
    o[4] = (short)f2bf(b.x); o[5] = (short)f2bf(b.y);
    o[6] = (short)f2bf(b.z); o[7] = (short)f2bf(b.w);
    *(bf16x8*)(dst + (size_t)g * 8) = o;
}

// bucketed CSR: entries[p*CAP + pos] = fid, cursor[p] = degree (doubles as counts)
__global__ void fill_kernel(const int* __restrict__ ci, int* __restrict__ cursor,
                            int* __restrict__ entries) {
    int fid = blockIdx.x * blockDim.x + threadIdx.x;
    if (fid >= NClause) return;
    int i0 = ci[fid * 3 + 0], i1 = ci[fid * 3 + 1], i2 = ci[fid * 3 + 2];
    int pos = atomicAdd(&cursor[i0], 1);
    entries[i0 * CAP + pos] = fid;
    if (i1 != i0) { pos = atomicAdd(&cursor[i1], 1); entries[i1 * CAP + pos] = fid; }
    if (i2 != i0 && i2 != i1) { pos = atomicAdd(&cursor[i2], 1); entries[i2 * CAP + pos] = fid; }
}

// M[fid][o] = bf16( sum_t meanG[fid][t]*Wcomb[o][t] + bias[o] )
// meanG = mean over 3 gathered rows of (vsb + msgs)
__global__ __launch_bounds__(256) void clause_kernel(
    const int* __restrict__ ci, const u16* __restrict__ vsb, const u16* __restrict__ msgs,
    const u16* __restrict__ Bpack, const float* __restrict__ bias, u16* __restrict__ M,
    int use_msgs) {
    __shared__ __align__(16) u16 Atile[64 * 136];   // 272B row pitch
    __shared__ __align__(16) u16 Btile[128 * 128];
    int tid = threadIdx.x;
    int block0 = blockIdx.x * 64;
    {   // stage packed B (32KB)
        const bf16x8* s = (const bf16x8*)Bpack;
        bf16x8* d = (bf16x8*)Btile;
#pragma unroll
        for (int i = 0; i < 8; ++i) d[tid + i * 256] = s[tid + i * 256];
    }
#pragma unroll
    for (int pass = 0; pass < 4; ++pass) {
        int t = pass * 256 + tid;
        int r = t >> 4, seg = t & 15;
        int fid = block0 + r;
        int b = fid / Cn;
        int i0 = ci[fid * 3 + 0], i1 = ci[fid * 3 + 1], i2 = ci[fid * 3 + 2];
        size_t vb = (size_t)b * Pn * Hdim;
        int co = seg * 8;
        bf16x8 v0 = *(const bf16x8*)(vsb + vb + (size_t)i0 * Hdim + co);
        bf16x8 v1 = *(const bf16x8*)(vsb + vb + (size_t)i1 * Hdim + co);
        bf16x8 v2 = *(const bf16x8*)(vsb + vb + (size_t)i2 * Hdim + co);
        float s[8];
#pragma unroll
        for (int j = 0; j < 8; ++j)
            s[j] = bf2f((u16)v0[j]) + bf2f((u16)v1[j]) + bf2f((u16)v2[j]);
        if (use_msgs) {
            bf16x8 m0 = *(const bf16x8*)(msgs + (size_t)i0 * Hdim + co);
            bf16x8 m1 = *(const bf16x8*)(msgs + (size_t)i1 * Hdim + co);
            bf16x8 m2 = *(const bf16x8*)(msgs + (size_t)i2 * Hdim + co);
#pragma unroll
            for (int j = 0; j < 8; ++j)
                s[j] += bf2f((u16)m0[j]) + bf2f((u16)m1[j]) + bf2f((u16)m2[j]);
        }
        bf16x8 o;
#pragma unroll
        for (int j = 0; j < 8; ++j) o[j] = (short)f2bf(s[j] * (1.f / 3.f));
        *(bf16x8*)(&Atile[r * 136 + seg * 8]) = o;
    }
    __syncthreads();
    int w = tid >> 6, l = tid & 63;
    int arow = w * 16 + (l & 15);
    int kofs = (l >> 4) * 8;
    f32x4 acc[8];
#pragma unroll
    for (int nt = 0; nt < 8; ++nt) acc[nt] = (f32x4){0.f, 0.f, 0.f, 0.f};
#pragma unroll
    for (int ks = 0; ks < 4; ++ks) {
        bf16x8 af = *(const bf16x8*)(&Atile[arow * 136 + ks * 32 + kofs]);
#pragma unroll
        for (int nt = 0; nt < 8; ++nt) {
            bf16x8 bfr = *(const bf16x8*)(&Btile[((nt * 4 + ks) * 64 + l) * 8]);
            acc[nt] = __builtin_amdgcn_mfma_f32_16x16x32_bf16(af, bfr, acc[nt], 0, 0, 0);
        }
    }
    __syncthreads();   // done reading Atile; reuse as output staging
    int crow = w * 16 + (l >> 4) * 4;
#pragma unroll
    for (int nt = 0; nt < 8; ++nt) {
        int col = nt * 16 + (l & 15);
        float bc = bias[col];
#pragma unroll
        for (int reg = 0; reg < 4; ++reg)
            Atile[(crow + reg) * 136 + col] = f2bf(acc[nt][reg] + bc);
    }
    __syncthreads();
#pragma unroll
    for (int pass = 0; pass < 4; ++pass) {
        int t = pass * 256 + tid;
        int r = t >> 4, seg = t & 15;
        *(bf16x8*)(M + (size_t)(block0 + r) * Hdim + seg * 8) =
            *(const bf16x8*)(&Atile[r * 136 + seg * 8]);
    }
}

// msgs[p] += mean over bucket entries of M[fid]
__global__ __launch_bounds__(256) void var_kernel(const u16* __restrict__ M,
                                                  const int* __restrict__ counts,
                                                  const int* __restrict__ entries,
                                                  u16* __restrict__ msgs) {
    int wave = threadIdx.x >> 6, lane = threadIdx.x & 63;
    int p = blockIdx.x * 4 + wave;
    if (p >= Pn) return;
    int deg = counts[p];
    const int* ep = entries + p * CAP;
    float a0 = 0.f, a1 = 0.f;
    for (int e = 0; e < deg; ++e) {
        int cid = ep[e];
        u32 v = *(const u32*)(M + (size_t)cid * Hdim + lane * 2);
        a0 += bf2f((u16)(v & 0xffffu));
        a1 += bf2f((u16)(v >> 16));
    }
    if (deg > 0) { float inv = 1.f / (float)deg; a0 *= inv; a1 *= inv; }
    u32* mp = (u32*)(msgs + (size_t)p * Hdim + lane * 2);
    u32 old = *mp;
    float o0 = bf2f((u16)(old & 0xffffu)) + a0;
    float o1 = bf2f((u16)(old >> 16)) + a1;
    *mp = (u32)f2bf(o0) | ((u32)f2bf(o1) << 16);
}

// out[row] = sigmoid( W_s2 . relu( (vsb[row]+msgs[row%Pn]) * W_s1^T + b_s1 ) + b_s2 )
__global__ __launch_bounds__(256) void final_kernel(
    const u16* __restrict__ vsb, const u16* __restrict__ msgs, const u16* __restrict__ Bpack,
    const float* __restrict__ b_s1, const float* __restrict__ W_s2, const float* __restrict__ b_s2,
    float* __restrict__ out) {
    __shared__ __align__(16) u16 Atile[64 * 136];
    __shared__ __align__(16) u16 Btile[128 * 128];
    int tid = threadIdx.x;
    int block0 = blockIdx.x * 64;
    {
        const bf16x8* s = (const bf16x8*)Bpack;
        bf16x8* d = (bf16x8*)Btile;
#pragma unroll
        for (int i = 0; i < 8; ++i) d[tid + i * 256] = s[tid + i * 256];
    }
#pragma unroll
    for (int pass = 0; pass < 4; ++pass) {
        int t = pass * 256 + tid;
        int r = t >> 4, seg = t & 15;
        int row = block0 + r;
        int p = row % Pn;
        int co = seg * 8;
        bf16x8 v = *(const bf16x8*)(vsb + (size_t)row * Hdim + co);
        bf16x8 m = *(const bf16x8*)(msgs + (size_t)p * Hdim + co);
        bf16x8 o;
#pragma unroll
        for (int j = 0; j < 8; ++j) o[j] = (short)f2bf(bf2f((u16)v[j]) + bf2f((u16)m[j]));
        *(bf16x8*)(&Atile[r * 136 + seg * 8]) = o;
    }
    __syncthreads();
    int w = tid >> 6, l = tid & 63;
    int arow = w * 16 + (l & 15);
    int kofs = (l >> 4) * 8;
    f32x4 acc[8];
#pragma unroll
    for (int nt = 0; nt < 8; ++nt) acc[nt] = (f32x4){0.f, 0.f, 0.f, 0.f};
#pragma unroll
    for (int ks = 0; ks < 4; ++ks) {
        bf16x8 af = *(const bf16x8*)(&Atile[arow * 136 + ks * 32 + kofs]);
#pragma unroll
        for (int nt = 0; nt < 8; ++nt) {
            bf16x8 bfr = *(const bf16x8*)(&Btile[((nt * 4 + ks) * 64 + l) * 8]);
            acc[nt] = __builtin_amdgcn_mfma_f32_16x16x32_bf16(af, bfr, acc[nt], 0, 0, 0);
        }
    }
    float part[4] = {0.f, 0.f, 0.f, 0.f};
#pragma unroll
    for (int nt = 0; nt < 8; ++nt) {
        int col = nt * 16 + (l & 15);
        float b1 = b_s1[col], w2 = W_s2[col];
#pragma unroll
        for (int reg = 0; reg < 4; ++reg)
            part[reg] += fmaxf(acc[nt][reg] + b1, 0.f) * w2;
    }
#pragma unroll
    for (int m = 1; m < 16; m <<= 1)
#pragma unroll
        for (int reg = 0; reg < 4; ++reg) part[reg] += __shfl_xor(part[reg], m, 64);
    if ((l & 15) == 0) {
        float lb = b_s2[0];
        int row0 = block0 + w * 16 + (l >> 4) * 4;
#pragma unroll
        for (int reg = 0; reg < 4; ++reg)
            out[row0 + reg] = 1.f / (1.f + expf(-(part[reg] + lb)));
    }
}

extern "C" void kernel_launch(void* const* d_in, const int* in_sizes, int n_in,
                              void* d_out, int out_size, void* d_ws, size_t ws_size,
                              hipStream_t stream) {
    (void)in_sizes; (void)n_in; (void)out_size; (void)ws_size;
    const int* ci = (const int*)d_in[0];
    const float* vs0 = (const float*)d_in[1];
    const float* W_vc = (const float*)d_in[2];
    const float* b_vc = (const float*)d_in[3];
    const float* W_ce = (const float*)d_in[4];
    const float* b_ce = (const float*)d_in[5];
    const float* W_cv = (const float*)d_in[6];
    const float* b_cv = (const float*)d_in[7];
    const float* W_s1 = (const float*)d_in[8];
    const float* b_s1 = (const float*)d_in[9];
    const float* W_s2 = (const float*)d_in[10];
    const float* b_s2 = (const float*)d_in[11];
    float* out = (float*)d_out;

    char* ws = (char*)d_ws;
    size_t off = 0;
    auto alloc = [&](size_t bytes) -> void* {
        off = (off + 255) & ~(size_t)255;
        void* p = ws + off;
        off += bytes;
        return p;
    };
    float* temp1 = (float*)alloc(Hdim * Hdim * 4);
    float* Wcomb = (float*)alloc(Hdim * Hdim * 4);
    float* bias_comb = (float*)alloc(Hdim * 4);
    u16* WcombPack = (u16*)alloc(Hdim * Hdim * 2);
    u16* Ws1Pack = (u16*)alloc(Hdim * Hdim * 2);
    int* cursor = (int*)alloc(Pn * 4);                      // degree per variable
    int* entries = (int*)alloc((size_t)Pn * CAP * 4);       // 12.8 MB bucketed CSR
    u16* M = (u16*)alloc((size_t)NClause * Hdim * 2);       // 20.5 MB
    u16* msgs = (u16*)alloc((size_t)Pn * Hdim * 2);         // 12.8 MB
    u16* vsb = (u16*)alloc((size_t)NRows * Hdim * 2);       // 51.2 MB

    hipMemsetAsync(cursor, 0, Pn * 4, stream);
    hipMemsetAsync(msgs, 0, (size_t)Pn * Hdim * 2, stream);

    // weight fold + pack
    mm128_kernel<<<Hdim, Hdim, 0, stream>>>(W_ce, W_vc, temp1);
    mm128_kernel<<<Hdim, Hdim, 0, stream>>>(W_cv, temp1, Wcomb);
    fold_bias_kernel<<<1, Hdim, 0, stream>>>(W_ce, b_vc, b_ce, W_cv, b_cv, bias_comb);
    pack_b_kernel<<<8, 256, 0, stream>>>(Wcomb, WcombPack);
    pack_b_kernel<<<8, 256, 0, stream>>>(W_s1, Ws1Pack);

    // bf16 copy of variable_states
    convert_kernel<<<(NRows * Hdim / 8) / 256, 256, 0, stream>>>(vs0, vsb);

    // bucketed CSR build (no scan needed)
    int nb = (NClause + 255) / 256;
    fill_kernel<<<nb, 256, 0, stream>>>(ci, cursor, entries);

    for (int it = 0; it < 2; ++it) {
        clause_kernel<<<NClause / 64, 256, 0, stream>>>(ci, vsb, msgs, WcombPack, bias_comb, M, it);
        var_kernel<<<(Pn + 3) / 4, 256, 0, stream>>>(M, cursor, entries, msgs);
    }
    final_kernel<<<NRows / 64, 256, 0, stream>>>(vsb, msgs, Ws1Pack, b_s1, W_s2, b_s2, out);
}

// Round 4
// 195.229 us; speedup vs baseline: 2.4299x; 1.0568x over previous
//
#include <hip/hip_runtime.h>
#include <math.h>

using u16 = unsigned short;
using u32 = unsigned int;

namespace {
constexpr int Hdim = 128;
constexpr int Pn = 50000;
constexpr int Cn = 20000;
constexpr int Bn = 4;
constexpr int NClause = Bn * Cn;   // 80000
constexpr int NRows = Bn * Pn;     // 200000
constexpr int CAP = 64;            // max clauses per variable (Binomial mean 4.8; P(>=64) ~ e^-150)
}

typedef __attribute__((ext_vector_type(4))) float f32x4;
typedef __attribute__((ext_vector_type(4))) int i32x4;
typedef __attribute__((ext_vector_type(8))) short bf16x8;

static __device__ __forceinline__ float bf2f(u16 v) {
    u32 u = ((u32)v) << 16;
    return __builtin_bit_cast(float, u);
}
static __device__ __forceinline__ u16 f2bf(float f) {
    u32 u = __builtin_bit_cast(u32, f);
    u32 r = u + 0x7FFFu + ((u >> 16) & 1u);
    return (u16)(r >> 16);
}

__global__ void zero_kernel(int* __restrict__ p, int n4) {
    int g = blockIdx.x * blockDim.x + threadIdx.x;
    if (g < n4) ((i32x4*)p)[g] = (i32x4){0, 0, 0, 0};
}

// C = A * B (128x128 fp32, row-major)
__global__ void mm128_kernel(const float* __restrict__ A, const float* __restrict__ Bm,
                             float* __restrict__ out) {
    int o = blockIdx.x, t = threadIdx.x;
    float acc = 0.f;
#pragma unroll 8
    for (int h = 0; h < Hdim; ++h) acc = fmaf(A[o * Hdim + h], Bm[h * Hdim + t], acc);
    out[o * Hdim + t] = acc;
}

// bias_comb = W_cv*(W_ce*b_vc + b_ce) + b_cv
__global__ void fold_bias_kernel(const float* __restrict__ W_ce, const float* __restrict__ b_vc,
                                 const float* __restrict__ b_ce, const float* __restrict__ W_cv,
                                 const float* __restrict__ b_cv, float* __restrict__ bias_comb) {
    __shared__ float b1[Hdim];
    int o = threadIdx.x;
    float acc = b_ce[o];
    for (int h = 0; h < Hdim; ++h) acc = fmaf(W_ce[o * Hdim + h], b_vc[h], acc);
    b1[o] = acc;
    __syncthreads();
    float acc2 = b_cv[o];
    for (int h = 0; h < Hdim; ++h) acc2 = fmaf(W_cv[o * Hdim + h], b1[h], acc2);
    bias_comb[o] = acc2;
}

// src is row-major [n][k] fp32 (i.e. B^T). Pack into per-lane MFMA B-frag layout:
// dst[((nt*4+ks)*64 + lane)*8 + j] = bf16(src[nt*16 + (lane&15)][ks*32 + (lane>>4)*8 + j])
__global__ void pack_b_kernel(const float* __restrict__ src, u16* __restrict__ dst) {
    int g = blockIdx.x * blockDim.x + threadIdx.x;   // 2048 total
    int lane = g & 63;
    int n = ((g >> 8) * 16) + (lane & 15);
    int k0 = ((g >> 6) & 3) * 32 + (lane >> 4) * 8;
    bf16x8 o;
#pragma unroll
    for (int j = 0; j < 8; ++j) o[j] = (short)f2bf(src[n * Hdim + k0 + j]);
    *(bf16x8*)(dst + (size_t)g * 8) = o;
}

__global__ void convert_kernel(const float* __restrict__ src, u16* __restrict__ dst) {
    int g = blockIdx.x * blockDim.x + threadIdx.x;   // one per 8 floats
    f32x4 a = ((const f32x4*)src)[(size_t)g * 2];
    f32x4 b = ((const f32x4*)src)[(size_t)g * 2 + 1];
    bf16x8 o;
    o[0] = (short)f2bf(a.x); o[1] = (short)f2bf(a.y);
    o[2] = (short)f2bf(a.z); o[3] = (short)f2bf(a.w);
    o[4] = (short)f2bf(b.x); o[5] = (short)f2bf(b.y);
    o[6] = (short)f2bf(b.z); o[7] = (short)f2bf(b.w);
    *(bf16x8*)(dst + (size_t)g * 8) = o;
}

// bucketed CSR: entries[p*CAP + pos] = fid, cursor[p] = degree (doubles as counts)
__global__ void fill_kernel(const int* __restrict__ ci, int* __restrict__ cursor,
                            int* __restrict__ entries) {
    int fid = blockIdx.x * blockDim.x + threadIdx.x;
    if (fid >= NClause) return;
    int i0 = ci[fid * 3 + 0], i1 = ci[fid * 3 + 1], i2 = ci[fid * 3 + 2];
    int pos = atomicAdd(&cursor[i0], 1);
    entries[i0 * CAP + pos] = fid;
    if (i1 != i0) { pos = atomicAdd(&cursor[i1], 1); entries[i1 * CAP + pos] = fid; }
    if (i2 != i0 && i2 != i1) { pos = atomicAdd(&cursor[i2], 1); entries[i2 * CAP + pos] = fid; }
}

// M[fid][o] = bf16( sum_t meanG[fid][t]*Wcomb[o][t] + bias[o] )
// meanG = mean over 3 gathered rows of (vsb + msgs)
__global__ __launch_bounds__(256) void clause_kernel(
    const int* __restrict__ ci, const u16* __restrict__ vsb, const u16* __restrict__ msgs,
    const u16* __restrict__ Bpack, const float* __restrict__ bias, u16* __restrict__ M,
    int use_msgs) {
    __shared__ __align__(16) u16 Atile[64 * 136];   // 272B row pitch
    __shared__ __align__(16) u16 Btile[128 * 128];
    int tid = threadIdx.x;
    int block0 = blockIdx.x * 64;
    {   // stage packed B (32KB)
        const bf16x8* s = (const bf16x8*)Bpack;
        bf16x8* d = (bf16x8*)Btile;
#pragma unroll
        for (int i = 0; i < 8; ++i) d[tid + i * 256] = s[tid + i * 256];
    }
#pragma unroll
    for (int pass = 0; pass < 4; ++pass) {
        int t = pass * 256 + tid;
        int r = t >> 4, seg = t & 15;
        int fid = block0 + r;
        int b = fid / Cn;
        int i0 = ci[fid * 3 + 0], i1 = ci[fid * 3 + 1], i2 = ci[fid * 3 + 2];
        size_t vb = (size_t)b * Pn * Hdim;
        int co = seg * 8;
        bf16x8 v0 = *(const bf16x8*)(vsb + vb + (size_t)i0 * Hdim + co);
        bf16x8 v1 = *(const bf16x8*)(vsb + vb + (size_t)i1 * Hdim + co);
        bf16x8 v2 = *(const bf16x8*)(vsb + vb + (size_t)i2 * Hdim + co);
        float s[8];
#pragma unroll
        for (int j = 0; j < 8; ++j)
            s[j] = bf2f((u16)v0[j]) + bf2f((u16)v1[j]) + bf2f((u16)v2[j]);
        if (use_msgs) {
            bf16x8 m0 = *(const bf16x8*)(msgs + (size_t)i0 * Hdim + co);
            bf16x8 m1 = *(const bf16x8*)(msgs + (size_t)i1 * Hdim + co);
            bf16x8 m2 = *(const bf16x8*)(msgs + (size_t)i2 * Hdim + co);
#pragma unroll
            for (int j = 0; j < 8; ++j)
                s[j] += bf2f((u16)m0[j]) + bf2f((u16)m1[j]) + bf2f((u16)m2[j]);
        }
        bf16x8 o;
#pragma unroll
        for (int j = 0; j < 8; ++j) o[j] = (short)f2bf(s[j] * (1.f / 3.f));
        *(bf16x8*)(&Atile[r * 136 + seg * 8]) = o;
    }
    __syncthreads();
    int w = tid >> 6, l = tid & 63;
    int arow = w * 16 + (l & 15);
    int kofs = (l >> 4) * 8;
    f32x4 acc[8];
#pragma unroll
    for (int nt = 0; nt < 8; ++nt) acc[nt] = (f32x4){0.f, 0.f, 0.f, 0.f};
#pragma unroll
    for (int ks = 0; ks < 4; ++ks) {
        bf16x8 af = *(const bf16x8*)(&Atile[arow * 136 + ks * 32 + kofs]);
#pragma unroll
        for (int nt = 0; nt < 8; ++nt) {
            bf16x8 bfr = *(const bf16x8*)(&Btile[((nt * 4 + ks) * 64 + l) * 8]);
            acc[nt] = __builtin_amdgcn_mfma_f32_16x16x32_bf16(af, bfr, acc[nt], 0, 0, 0);
        }
    }
    __syncthreads();   // done reading Atile; reuse as output staging
    int crow = w * 16 + (l >> 4) * 4;
#pragma unroll
    for (int nt = 0; nt < 8; ++nt) {
        int col = nt * 16 + (l & 15);
        float bc = bias[col];
#pragma unroll
        for (int reg = 0; reg < 4; ++reg)
            Atile[(crow + reg) * 136 + col] = f2bf(acc[nt][reg] + bc);
    }
    __syncthreads();
#pragma unroll
    for (int pass = 0; pass < 4; ++pass) {
        int t = pass * 256 + tid;
        int r = t >> 4, seg = t & 15;
        *(bf16x8*)(M + (size_t)(block0 + r) * Hdim + seg * 8) =
            *(const bf16x8*)(&Atile[r * 136 + seg * 8]);
    }
}

// msgs[p] (first ? = : +=) mean over bucket entries of M[fid]
__global__ __launch_bounds__(256) void var_kernel(const u16* __restrict__ M,
                                                  const int* __restrict__ counts,
                                                  const int* __restrict__ entries,
                                                  u16* __restrict__ msgs, int first) {
    int wave = threadIdx.x >> 6, lane = threadIdx.x & 63;
    int p = blockIdx.x * 4 + wave;
    if (p >= Pn) return;
    int deg = counts[p];
    const int* ep = entries + p * CAP;
    float a0 = 0.f, a1 = 0.f;
    for (int e = 0; e < deg; ++e) {
        int cid = ep[e];
        u32 v = *(const u32*)(M + (size_t)cid * Hdim + lane * 2);
        a0 += bf2f((u16)(v & 0xffffu));
        a1 += bf2f((u16)(v >> 16));
    }
    if (deg > 0) { float inv = 1.f / (float)deg; a0 *= inv; a1 *= inv; }
    u32* mp = (u32*)(msgs + (size_t)p * Hdim + lane * 2);
    if (!first) {
        u32 old = *mp;
        a0 += bf2f((u16)(old & 0xffffu));
        a1 += bf2f((u16)(old >> 16));
    }
    *mp = (u32)f2bf(a0) | ((u32)f2bf(a1) << 16);
}

// out[row] = sigmoid( W_s2 . relu( (vsb[row]+msgs[row%Pn]) * W_s1^T + b_s1 ) + b_s2 )
__global__ __launch_bounds__(256) void final_kernel(
    const u16* __restrict__ vsb, const u16* __restrict__ msgs, const u16* __restrict__ Bpack,
    const float* __restrict__ b_s1, const float* __restrict__ W_s2, const float* __restrict__ b_s2,
    float* __restrict__ out) {
    __shared__ __align__(16) u16 Atile[64 * 136];
    __shared__ __align__(16) u16 Btile[128 * 128];
    int tid = threadIdx.x;
    int block0 = blockIdx.x * 64;
    {
        const bf16x8* s = (const bf16x8*)Bpack;
        bf16x8* d = (bf16x8*)Btile;
#pragma unroll
        for (int i = 0; i < 8; ++i) d[tid + i * 256] = s[tid + i * 256];
    }
#pragma unroll
    for (int pass = 0; pass < 4; ++pass) {
        int t = pass * 256 + tid;
        int r = t >> 4, seg = t & 15;
        int row = block0 + r;
        int p = row % Pn;
        int co = seg * 8;
        bf16x8 v = *(const bf16x8*)(vsb + (size_t)row * Hdim + co);
        bf16x8 m = *(const bf16x8*)(msgs + (size_t)p * Hdim + co);
        bf16x8 o;
#pragma unroll
        for (int j = 0; j < 8; ++j) o[j] = (short)f2bf(bf2f((u16)v[j]) + bf2f((u16)m[j]));
        *(bf16x8*)(&Atile[r * 136 + seg * 8]) = o;
    }
    __syncthreads();
    int w = tid >> 6, l = tid & 63;
    int arow = w * 16 + (l & 15);
    int kofs = (l >> 4) * 8;
    f32x4 acc[8];
#pragma unroll
    for (int nt = 0; nt < 8; ++nt) acc[nt] = (f32x4){0.f, 0.f, 0.f, 0.f};
#pragma unroll
    for (int ks = 0; ks < 4; ++ks) {
        bf16x8 af = *(const bf16x8*)(&Atile[arow * 136 + ks * 32 + kofs]);
#pragma unroll
        for (int nt = 0; nt < 8; ++nt) {
            bf16x8 bfr = *(const bf16x8*)(&Btile[((nt * 4 + ks) * 64 + l) * 8]);
            acc[nt] = __builtin_amdgcn_mfma_f32_16x16x32_bf16(af, bfr, acc[nt], 0, 0, 0);
        }
    }
    float part[4] = {0.f, 0.f, 0.f, 0.f};
#pragma unroll
    for (int nt = 0; nt < 8; ++nt) {
        int col = nt * 16 + (l & 15);
        float b1 = b_s1[col], w2 = W_s2[col];
#pragma unroll
        for (int reg = 0; reg < 4; ++reg)
            part[reg] += fmaxf(acc[nt][reg] + b1, 0.f) * w2;
    }
#pragma unroll
    for (int m = 1; m < 16; m <<= 1)
#pragma unroll
        for (int reg = 0; reg < 4; ++reg) part[reg] += __shfl_xor(part[reg], m, 64);
    if ((l & 15) == 0) {
        float lb = b_s2[0];
        int row0 = block0 + w * 16 + (l >> 4) * 4;
#pragma unroll
        for (int reg = 0; reg < 4; ++reg)
            out[row0 + reg] = 1.f / (1.f + expf(-(part[reg] + lb)));
    }
}

extern "C" void kernel_launch(void* const* d_in, const int* in_sizes, int n_in,
                              void* d_out, int out_size, void* d_ws, size_t ws_size,
                              hipStream_t stream) {
    (void)in_sizes; (void)n_in; (void)out_size; (void)ws_size;
    const int* ci = (const int*)d_in[0];
    const float* vs0 = (const float*)d_in[1];
    const float* W_vc = (const float*)d_in[2];
    const float* b_vc = (const float*)d_in[3];
    const float* W_ce = (const float*)d_in[4];
    const float* b_ce = (const float*)d_in[5];
    const float* W_cv = (const float*)d_in[6];
    const float* b_cv = (const float*)d_in[7];
    const float* W_s1 = (const float*)d_in[8];
    const float* b_s1 = (const float*)d_in[9];
    const float* W_s2 = (const float*)d_in[10];
    const float* b_s2 = (const float*)d_in[11];
    float* out = (float*)d_out;

    char* ws = (char*)d_ws;
    size_t off = 0;
    auto alloc = [&](size_t bytes) -> void* {
        off = (off + 255) & ~(size_t)255;
        void* p = ws + off;
        off += bytes;
        return p;
    };
    float* temp1 = (float*)alloc(Hdim * Hdim * 4);
    float* Wcomb = (float*)alloc(Hdim * Hdim * 4);
    float* bias_comb = (float*)alloc(Hdim * 4);
    u16* WcombPack = (u16*)alloc(Hdim * Hdim * 2);
    u16* Ws1Pack = (u16*)alloc(Hdim * Hdim * 2);
    int* cursor = (int*)alloc(Pn * 4);                      // degree per variable
    int* entries = (int*)alloc((size_t)Pn * CAP * 4);       // 12.8 MB bucketed CSR
    u16* M = (u16*)alloc((size_t)NClause * Hdim * 2);       // 20.5 MB
    u16* msgs = (u16*)alloc((size_t)Pn * Hdim * 2);         // 12.8 MB
    u16* vsb = (u16*)alloc((size_t)NRows * Hdim * 2);       // 51.2 MB

    // zero cursor with our own kernel (in-graph hipMemsetAsync costs ~58us!)
    zero_kernel<<<(Pn / 4 + 255) / 256, 256, 0, stream>>>(cursor, Pn / 4);

    // weight fold + pack
    mm128_kernel<<<Hdim, Hdim, 0, stream>>>(W_ce, W_vc, temp1);
    mm128_kernel<<<Hdim, Hdim, 0, stream>>>(W_cv, temp1, Wcomb);
    fold_bias_kernel<<<1, Hdim, 0, stream>>>(W_ce, b_vc, b_ce, W_cv, b_cv, bias_comb);
    pack_b_kernel<<<8, 256, 0, stream>>>(Wcomb, WcombPack);
    pack_b_kernel<<<8, 256, 0, stream>>>(W_s1, Ws1Pack);

    // bf16 copy of variable_states
    convert_kernel<<<(NRows * Hdim / 8) / 256, 256, 0, stream>>>(vs0, vsb);

    // bucketed CSR build (no scan needed)
    int nb = (NClause + 255) / 256;
    fill_kernel<<<nb, 256, 0, stream>>>(ci, cursor, entries);

    for (int it = 0; it < 2; ++it) {
        clause_kernel<<<NClause / 64, 256, 0, stream>>>(ci, vsb, msgs, WcombPack, bias_comb, M, it);
        var_kernel<<<(Pn + 3) / 4, 256, 0, stream>>>(M, cursor, entries, msgs, it == 0 ? 1 : 0);
    }
    final_kernel<<<NRows / 64, 256, 0, stream>>>(vsb, msgs, Ws1Pack, b_s1, W_s2, b_s2, out);
}